// Round 3
// baseline (2759.097 us; speedup 1.0000x reference)
//
#include <hip/hip_runtime.h>

typedef _Float16 f16;
typedef _Float16 f16x2 __attribute__((ext_vector_type(2)));
typedef _Float16 f16x8 __attribute__((ext_vector_type(8)));

#if __has_builtin(__builtin_amdgcn_fdot2)
__device__ __forceinline__ float fdot2f(f16x2 a, f16x2 b, float c) {
  return __builtin_amdgcn_fdot2(a, b, c, false);
}
#else
__device__ __forceinline__ float fdot2f(f16x2 a, f16x2 b, float c) {
  return c + (float)a[0] * (float)b[0] + (float)a[1] * (float)b[1];
}
#endif

__device__ __forceinline__ float sigm(float z) { return 1.0f / (1.0f + __expf(-z)); }
__device__ __forceinline__ float tanhq(float z) {
  float e = __expf(-2.0f * z);
  return (1.0f - e) / (1.0f + e);
}

#define TT 512
#define W0_STRIDE 74   /* [Whh0(64) | Wih0(6) | zeros(2) | pad(2)], odd dword stride (37) -> conflict-free b32 reads */
#define W1_STRIDE 130  /* [Whh1(64) | Wih1(64) | zeros(2)], odd dword stride (65) */
#define W0_ELEMS (256 * W0_STRIDE)
#define W1_ELEMS (256 * W1_STRIDE)
#define HB_OFF (W0_ELEMS + W1_ELEMS)              /* 52224 f16 elems */
#define HB_STRIDE 144                              /* per-batch aug vec: [h2(64) | h1(64) | x(6) | 0(2) | pad], 288B (16B-aligned rows) */
#define GEX_OFF_F16 (HB_OFF + 2 * 4 * HB_STRIDE)  /* 53376 */
#define LDS_BYTES (GEX_OFF_F16 * 2 + 2048 * 4)    /* 114944 B */

__global__ __launch_bounds__(512, 1)
void lstm2_kernel(const float* __restrict__ x,
                  const float* __restrict__ Wih0, const float* __restrict__ Whh0,
                  const float* __restrict__ bih0, const float* __restrict__ bhh0,
                  const float* __restrict__ Wih1, const float* __restrict__ Whh1,
                  const float* __restrict__ bih1, const float* __restrict__ bhh1,
                  const float* __restrict__ Wlin, const float* __restrict__ blin,
                  float* __restrict__ out)
{
  extern __shared__ f16 lds[];
  f16* W0 = lds;                       // [256][74] f16
  f16* W1 = lds + W0_ELEMS;            // [256][130] f16
  f16* hb_all = lds + HB_OFF;          // [2 groups][4 batch][144] f16
  float* gex = (float*)(lds + GEX_OFF_F16);  // [2][4 gate][4 batch][64] f32

  const int tid = threadIdx.x;
  const int wv = tid >> 6;        // wave 0..7
  const int lane = tid & 63;
  const int g = wv >> 2;          // group 0..1 (4 batch rows each)
  const int w = wv & 3;           // gate block (i,f,g,o) AND the batch this wave owns for pointwise
  const int bmine = blockIdx.x * 8 + g * 4 + w;

  // ---- stage weights to LDS as fp16 (augmented layouts) ----
  for (int idx = tid; idx < W0_ELEMS; idx += 512) {
    int r = idx / W0_STRIDE, c = idx - r * W0_STRIDE;
    float v = (c < 64) ? Whh0[r * 64 + c] : ((c < 70) ? Wih0[r * 6 + (c - 64)] : 0.0f);
    W0[idx] = (f16)v;
  }
  for (int idx = tid; idx < W1_ELEMS; idx += 512) {
    int r = idx / W1_STRIDE, c = idx - r * W1_STRIDE;
    float v = (c < 64) ? Whh1[r * 64 + c] : ((c < 128) ? Wih1[r * 64 + (c - 64)] : 0.0f);
    W1[idx] = (f16)v;
  }
  for (int idx = tid; idx < 2 * 4 * HB_STRIDE; idx += 512) hb_all[idx] = (f16)0.0f;
  __syncthreads();

  // x(t=0) preload: wave w writes its own batch's x slot
  if (lane < 6) {
    hb_all[(g * 4 + w) * HB_STRIDE + 128 + lane] = (f16)x[(size_t)bmine * (TT * 6) + lane];
  }

  const int r = w * 64 + lane;    // this lane's gate row (0..255)
  const float bias0 = bih0[r] + bhh0[r];
  const float bias1 = bih1[r] + bhh1[r];
  float c1 = 0.0f, c2 = 0.0f;
  const f16* wr0 = &W0[r * W0_STRIDE];
  const f16* wr1 = &W1[r * W1_STRIDE];
  const f16* hbg = &hb_all[g * 4 * HB_STRIDE];
  f16* hmine = &hb_all[(g * 4 + w) * HB_STRIDE];
  float* gexg = &gex[g * 1024];

  __syncthreads();

  for (int t = 0; t < TT; ++t) {
    // ======== layer 0 gate matvec: gates0 = bias0 + W0aug . [h1_prev | x_t] ========
    float acc0 = bias0, acc1 = bias0, acc2 = bias0, acc3 = bias0;
    #pragma unroll 3
    for (int q4 = 0; q4 < 9; ++q4) {
      f16x2 wa = *(const f16x2*)&wr0[8 * q4 + 0];
      f16x2 wb = *(const f16x2*)&wr0[8 * q4 + 2];
      f16x2 wc = *(const f16x2*)&wr0[8 * q4 + 4];
      f16x2 wd = *(const f16x2*)&wr0[8 * q4 + 6];
      #pragma unroll
      for (int b = 0; b < 4; ++b) {
        f16x8 hv = *(const f16x8*)&hbg[b * HB_STRIDE + 64 + 8 * q4];
        f16x2 p0 = __builtin_shufflevector(hv, hv, 0, 1);
        f16x2 p1 = __builtin_shufflevector(hv, hv, 2, 3);
        f16x2 p2 = __builtin_shufflevector(hv, hv, 4, 5);
        f16x2 p3 = __builtin_shufflevector(hv, hv, 6, 7);
        float a = (b == 0) ? acc0 : (b == 1) ? acc1 : (b == 2) ? acc2 : acc3;
        a = fdot2f(wa, p0, a);
        a = fdot2f(wb, p1, a);
        a = fdot2f(wc, p2, a);
        a = fdot2f(wd, p3, a);
        if (b == 0) acc0 = a; else if (b == 1) acc1 = a; else if (b == 2) acc2 = a; else acc3 = a;
      }
    }
    {
      float a0 = (w == 2) ? tanhq(acc0) : sigm(acc0);
      float a1 = (w == 2) ? tanhq(acc1) : sigm(acc1);
      float a2 = (w == 2) ? tanhq(acc2) : sigm(acc2);
      float a3 = (w == 2) ? tanhq(acc3) : sigm(acc3);
      gexg[w * 256 + 0 * 64 + lane] = a0;
      gexg[w * 256 + 1 * 64 + lane] = a1;
      gexg[w * 256 + 2 * 64 + lane] = a2;
      gexg[w * 256 + 3 * 64 + lane] = a3;
    }
    __syncthreads();
    // ======== layer 0 pointwise (wave w handles batch w, lane = hidden unit) ========
    {
      float iv = gexg[0 * 256 + w * 64 + lane];
      float fv = gexg[1 * 256 + w * 64 + lane];
      float gv = gexg[2 * 256 + w * 64 + lane];
      float ov = gexg[3 * 256 + w * 64 + lane];
      c1 = fv * c1 + iv * gv;
      float h1v = ov * tanhq(c1);
      hmine[64 + lane] = (f16)h1v;
    }
    __syncthreads();
    // ======== layer 1 gate matvec: gates1 = bias1 + W1aug . [h2_prev | h1_cur] ========
    acc0 = bias1; acc1 = bias1; acc2 = bias1; acc3 = bias1;
    #pragma unroll 4
    for (int q4 = 0; q4 < 16; ++q4) {
      f16x2 wa = *(const f16x2*)&wr1[8 * q4 + 0];
      f16x2 wb = *(const f16x2*)&wr1[8 * q4 + 2];
      f16x2 wc = *(const f16x2*)&wr1[8 * q4 + 4];
      f16x2 wd = *(const f16x2*)&wr1[8 * q4 + 6];
      #pragma unroll
      for (int b = 0; b < 4; ++b) {
        f16x8 hv = *(const f16x8*)&hbg[b * HB_STRIDE + 8 * q4];
        f16x2 p0 = __builtin_shufflevector(hv, hv, 0, 1);
        f16x2 p1 = __builtin_shufflevector(hv, hv, 2, 3);
        f16x2 p2 = __builtin_shufflevector(hv, hv, 4, 5);
        f16x2 p3 = __builtin_shufflevector(hv, hv, 6, 7);
        float a = (b == 0) ? acc0 : (b == 1) ? acc1 : (b == 2) ? acc2 : acc3;
        a = fdot2f(wa, p0, a);
        a = fdot2f(wb, p1, a);
        a = fdot2f(wc, p2, a);
        a = fdot2f(wd, p3, a);
        if (b == 0) acc0 = a; else if (b == 1) acc1 = a; else if (b == 2) acc2 = a; else acc3 = a;
      }
    }
    {
      float a0 = (w == 2) ? tanhq(acc0) : sigm(acc0);
      float a1 = (w == 2) ? tanhq(acc1) : sigm(acc1);
      float a2 = (w == 2) ? tanhq(acc2) : sigm(acc2);
      float a3 = (w == 2) ? tanhq(acc3) : sigm(acc3);
      gexg[w * 256 + 0 * 64 + lane] = a0;
      gexg[w * 256 + 1 * 64 + lane] = a1;
      gexg[w * 256 + 2 * 64 + lane] = a2;
      gexg[w * 256 + 3 * 64 + lane] = a3;
    }
    __syncthreads();
    // ======== layer 1 pointwise + x(t+1) prefetch ========
    {
      float iv = gexg[0 * 256 + w * 64 + lane];
      float fv = gexg[1 * 256 + w * 64 + lane];
      float gv = gexg[2 * 256 + w * 64 + lane];
      float ov = gexg[3 * 256 + w * 64 + lane];
      c2 = fv * c2 + iv * gv;
      float h2v = ov * tanhq(c2);
      hmine[lane] = (f16)h2v;
      if (lane < 6 && t + 1 < TT) {
        hmine[128 + lane] = (f16)x[(size_t)bmine * (TT * 6) + (size_t)(t + 1) * 6 + lane];
      }
    }
    __syncthreads();
  }

  // ======== final linear: out[b] = Wlin . h2_T + blin (wave w -> batch w, lanes 0..5) ========
  if (lane < 6) {
    float a = blin[lane];
    const float* wl = &Wlin[lane * 64];
    #pragma unroll 8
    for (int u = 0; u < 64; ++u) a += wl[u] * (float)hmine[u];
    out[bmine * 6 + lane] = a;
  }
}

extern "C" void kernel_launch(void* const* d_in, const int* in_sizes, int n_in,
                              void* d_out, int out_size, void* d_ws, size_t ws_size,
                              hipStream_t stream) {
  const float* xp    = (const float*)d_in[0];
  const float* Wih0  = (const float*)d_in[1];
  const float* Whh0  = (const float*)d_in[2];
  const float* bih0  = (const float*)d_in[3];
  const float* bhh0  = (const float*)d_in[4];
  const float* Wih1  = (const float*)d_in[5];
  const float* Whh1  = (const float*)d_in[6];
  const float* bih1  = (const float*)d_in[7];
  const float* bhh1  = (const float*)d_in[8];
  const float* Wlin  = (const float*)d_in[9];
  const float* blin  = (const float*)d_in[10];
  float* outp = (float*)d_out;

  hipFuncSetAttribute(reinterpret_cast<const void*>(lstm2_kernel),
                      hipFuncAttributeMaxDynamicSharedMemorySize, LDS_BYTES);
  lstm2_kernel<<<256, 512, LDS_BYTES, stream>>>(xp, Wih0, Whh0, bih0, bhh0,
                                                Wih1, Whh1, bih1, bhh1,
                                                Wlin, blin, outp);
}

// Round 5
// 1526.161 us; speedup vs baseline: 1.8079x; 1.8079x over previous
//
#include <hip/hip_runtime.h>

typedef _Float16 f16;
typedef _Float16 f16x2 __attribute__((ext_vector_type(2)));
typedef _Float16 f16x8 __attribute__((ext_vector_type(8)));

#if __has_builtin(__builtin_amdgcn_fdot2)
__device__ __forceinline__ float fdot2f(f16x2 a, f16x2 b, float c) {
  return __builtin_amdgcn_fdot2(a, b, c, false);
}
#else
__device__ __forceinline__ float fdot2f(f16x2 a, f16x2 b, float c) {
  return c + (float)a[0] * (float)b[0] + (float)a[1] * (float)b[1];
}
#endif

__device__ __forceinline__ float sigm(float z) { return 1.0f / (1.0f + __expf(-z)); }
__device__ __forceinline__ float tanhq(float z) {
  float e = __expf(-2.0f * z);
  return (1.0f - e) / (1.0f + e);
}

__device__ __forceinline__ float dot8(f16x8 wv, f16x8 v, float a) {
  a = fdot2f(__builtin_shufflevector(wv, wv, 0, 1), __builtin_shufflevector(v, v, 0, 1), a);
  a = fdot2f(__builtin_shufflevector(wv, wv, 2, 3), __builtin_shufflevector(v, v, 2, 3), a);
  a = fdot2f(__builtin_shufflevector(wv, wv, 4, 5), __builtin_shufflevector(v, v, 4, 5), a);
  a = fdot2f(__builtin_shufflevector(wv, wv, 6, 7), __builtin_shufflevector(v, v, 6, 7), a);
  return a;
}

#define TT 512
// LDS layout (f16 element offsets)
#define W0S 72              /* row: [Whh0(64) | Wih0(6) | 0,0] = 144B, odd multiple of 16B -> uniform quad spread */
#define W1S 136             /* row: [Whh1(64) | Wih1(64) | pad(8)] = 272B, odd multiple of 16B */
#define W0_ELE (256 * W0S)  /* 18432 */
#define W1_OFF W0_ELE
#define W1_ELE (256 * W1S)  /* 34816 */
#define HB_OFF (W1_OFF + W1_ELE)   /* 53248 ; per batch [h2(64)|h1(64)] = 128 f16 (256B) */
#define XL_OFF (HB_OFF + 8 * 128)  /* 54272 ; x staged f16 [8 batch][512 t][6] */
#define XL_ELE (8 * TT * 6)        /* 24576 */
#define LDS_F16 (XL_OFF + XL_ELE)  /* 78848 f16 */
#define LDS_BYTES (LDS_F16 * 2)    /* 157696 B (<= 160 KiB) */

__global__ __launch_bounds__(256, 1)
void lstm2_kernel(const float* __restrict__ x,
                  const float* __restrict__ Wih0, const float* __restrict__ Whh0,
                  const float* __restrict__ bih0, const float* __restrict__ bhh0,
                  const float* __restrict__ Wih1, const float* __restrict__ Whh1,
                  const float* __restrict__ bih1, const float* __restrict__ bhh1,
                  const float* __restrict__ Wlin, const float* __restrict__ blin,
                  float* __restrict__ out)
{
  extern __shared__ f16 lds[];
  const int tid = threadIdx.x;
  const int w = tid >> 6;        // wave 0..3, owns batches 2w, 2w+1
  const int j = tid & 63;        // hidden unit owned by this lane

  // ---- stage weights: thread tid stages row tid of W0 and W1 ----
  {
    const int r = tid;
    f16* d0 = &lds[r * W0S];
    const float* s0 = &Whh0[r * 64];
    #pragma unroll 8
    for (int c = 0; c < 64; ++c) d0[c] = (f16)s0[c];
    #pragma unroll
    for (int c = 0; c < 6; ++c) d0[64 + c] = (f16)Wih0[r * 6 + c];
    d0[70] = (f16)0.0f; d0[71] = (f16)0.0f;

    f16* d1 = &lds[W1_OFF + r * W1S];
    const float* s1 = &Whh1[r * 64];
    const float* s2 = &Wih1[r * 64];
    #pragma unroll 8
    for (int c = 0; c < 64; ++c) d1[c] = (f16)s1[c];
    #pragma unroll 8
    for (int c = 0; c < 64; ++c) d1[64 + c] = (f16)s2[c];
    #pragma unroll
    for (int c = 128; c < 136; ++c) d1[c] = (f16)0.0f;
  }
  // ---- stage x (f16) for this block's 8 batches: perfectly coalesced ----
  {
    const float* xblk = x + (size_t)blockIdx.x * 8 * (TT * 6);
    for (int idx = tid; idx < XL_ELE; idx += 256) lds[XL_OFF + idx] = (f16)xblk[idx];
  }
  // ---- zero h state ----
  for (int idx = tid; idx < 8 * 128; idx += 256) lds[HB_OFF + idx] = (f16)0.0f;
  __syncthreads();   // the only block-wide barrier

  // per-lane weight row bases (gate g row = g*64 + j)
  const f16* w0r[4]; const f16* w1r[4];
  float bias0[4], bias1[4];
  #pragma unroll
  for (int g = 0; g < 4; ++g) {
    w0r[g] = &lds[(g * 64 + j) * W0S];
    w1r[g] = &lds[W1_OFF + (g * 64 + j) * W1S];
    bias0[g] = bih0[g * 64 + j] + bhh0[g * 64 + j];
    bias1[g] = bih1[g * 64 + j] + bhh1[g * 64 + j];
  }
  f16* hbP[2] = { &lds[HB_OFF + (w * 2 + 0) * 128], &lds[HB_OFF + (w * 2 + 1) * 128] };
  const f16* xlP[2] = { &lds[XL_OFF + (w * 2 + 0) * (TT * 6)], &lds[XL_OFF + (w * 2 + 1) * (TT * 6)] };

  float c1[2] = {0.0f, 0.0f}, c2[2] = {0.0f, 0.0f};

  #pragma unroll 1
  for (int t = 0; t < TT; ++t) {
    // x_t pairs (broadcast reads, f16)
    f16x2 xp[2][3];
    #pragma unroll
    for (int b = 0; b < 2; ++b) {
      const f16* xb = &xlP[b][t * 6];
      xp[b][0] = *(const f16x2*)&xb[0];
      xp[b][1] = *(const f16x2*)&xb[2];
      xp[b][2] = *(const f16x2*)&xb[4];
    }

    // ======== layer 0: gates = bias0 + Whh0.h1_prev + Wih0.x_t ========
    float acc[2][4];
    #pragma unroll
    for (int b = 0; b < 2; ++b)
      #pragma unroll
      for (int g = 0; g < 4; ++g) acc[b][g] = bias0[g];

    #pragma unroll
    for (int c = 0; c < 8; ++c) {
      f16x8 wv[4];
      #pragma unroll
      for (int g = 0; g < 4; ++g) wv[g] = *(const f16x8*)&w0r[g][8 * c];
      f16x8 hv[2];
      #pragma unroll
      for (int b = 0; b < 2; ++b) hv[b] = *(const f16x8*)&hbP[b][64 + 8 * c];
      #pragma unroll
      for (int b = 0; b < 2; ++b)
        #pragma unroll
        for (int g = 0; g < 4; ++g) acc[b][g] = dot8(wv[g], hv[b], acc[b][g]);
    }
    #pragma unroll
    for (int g = 0; g < 4; ++g) {
      f16x8 wx = *(const f16x8*)&w0r[g][64];
      f16x2 w01 = __builtin_shufflevector(wx, wx, 0, 1);
      f16x2 w23 = __builtin_shufflevector(wx, wx, 2, 3);
      f16x2 w45 = __builtin_shufflevector(wx, wx, 4, 5);
      #pragma unroll
      for (int b = 0; b < 2; ++b) {
        acc[b][g] = fdot2f(w01, xp[b][0], acc[b][g]);
        acc[b][g] = fdot2f(w23, xp[b][1], acc[b][g]);
        acc[b][g] = fdot2f(w45, xp[b][2], acc[b][g]);
      }
    }
    // layer 0 pointwise (lane-local) + h1 write
    #pragma unroll
    for (int b = 0; b < 2; ++b) {
      float iv = sigm(acc[b][0]);
      float fv = sigm(acc[b][1]);
      float gv = tanhq(acc[b][2]);
      float ov = sigm(acc[b][3]);
      float cn = fv * c1[b] + iv * gv;
      c1[b] = cn;
      hbP[b][64 + j] = (f16)(ov * tanhq(cn));
    }

    // ======== layer 1: gates = bias1 + Whh1.h2_prev + Wih1.h1_cur ========
    #pragma unroll
    for (int b = 0; b < 2; ++b)
      #pragma unroll
      for (int g = 0; g < 4; ++g) acc[b][g] = bias1[g];

    #pragma unroll
    for (int c = 0; c < 16; ++c) {
      f16x8 wv[4];
      #pragma unroll
      for (int g = 0; g < 4; ++g) wv[g] = *(const f16x8*)&w1r[g][8 * c];
      f16x8 hv[2];
      #pragma unroll
      for (int b = 0; b < 2; ++b) hv[b] = *(const f16x8*)&hbP[b][8 * c];
      #pragma unroll
      for (int b = 0; b < 2; ++b)
        #pragma unroll
        for (int g = 0; g < 4; ++g) acc[b][g] = dot8(wv[g], hv[b], acc[b][g]);
    }
    // layer 1 pointwise + h2 write
    #pragma unroll
    for (int b = 0; b < 2; ++b) {
      float iv = sigm(acc[b][0]);
      float fv = sigm(acc[b][1]);
      float gv = tanhq(acc[b][2]);
      float ov = sigm(acc[b][3]);
      float cn = fv * c2[b] + iv * gv;
      c2[b] = cn;
      hbP[b][j] = (f16)(ov * tanhq(cn));
    }
  }

  // ======== final linear: out[b] = Wlin . h2_T + blin ========
  if (j < 6) {
    #pragma unroll
    for (int b = 0; b < 2; ++b) {
      const int bg = blockIdx.x * 8 + w * 2 + b;
      float a = blin[j];
      const float* wl = &Wlin[j * 64];
      #pragma unroll 8
      for (int u = 0; u < 64; ++u) a += wl[u] * (float)hbP[b][u];
      out[bg * 6 + j] = a;
    }
  }
}

extern "C" void kernel_launch(void* const* d_in, const int* in_sizes, int n_in,
                              void* d_out, int out_size, void* d_ws, size_t ws_size,
                              hipStream_t stream) {
  const float* xp    = (const float*)d_in[0];
  const float* Wih0  = (const float*)d_in[1];
  const float* Whh0  = (const float*)d_in[2];
  const float* bih0  = (const float*)d_in[3];
  const float* bhh0  = (const float*)d_in[4];
  const float* Wih1  = (const float*)d_in[5];
  const float* Whh1  = (const float*)d_in[6];
  const float* bih1  = (const float*)d_in[7];
  const float* bhh1  = (const float*)d_in[8];
  const float* Wlin  = (const float*)d_in[9];
  const float* blin  = (const float*)d_in[10];
  float* outp = (float*)d_out;

  hipFuncSetAttribute(reinterpret_cast<const void*>(lstm2_kernel),
                      hipFuncAttributeMaxDynamicSharedMemorySize, LDS_BYTES);
  lstm2_kernel<<<256, 256, LDS_BYTES, stream>>>(xp, Wih0, Whh0, bih0, bhh0,
                                                Wih1, Whh1, bih1, bhh1,
                                                Wlin, blin, outp);
}

// Round 7
// 836.925 us; speedup vs baseline: 3.2967x; 1.8235x over previous
//
#include <hip/hip_runtime.h>

typedef _Float16 f16;
typedef _Float16 f16x4 __attribute__((ext_vector_type(4)));
typedef _Float16 f16x8 __attribute__((ext_vector_type(8)));
typedef float f32x4 __attribute__((ext_vector_type(4)));

__device__ __forceinline__ float sigm(float z) { return 1.0f / (1.0f + __expf(-z)); }
__device__ __forceinline__ float tanhq(float z) {
  float e = __expf(-2.0f * z);
  return (1.0f - e) / (1.0f + e);
}

#define TT 512
#define NB 16                 /* batches per block */
#define AUGS 168              /* aug row stride (f16): [h2(64)|h1(64)|x(6)|zeros(26)|slack(8)] ; 336B = 84dw -> <=2-way banks */
#define XS_ELE (NB * TT * 6)  /* 49152 f16 */
#define A0OFF XS_ELE
#define A1OFF (A0OFF + NB * AUGS)
#define LDS_F16 (A1OFF + NB * AUGS)   /* 54528 */
#define LDS_BYTES (LDS_F16 * 2)       /* 109056 B */

__device__ __forceinline__ f16x8 cvt8(const float* p) {
  f32x4 a = *(const f32x4*)p;
  f32x4 b = *(const f32x4*)(p + 4);
  f16x8 r;
  #pragma unroll
  for (int i = 0; i < 4; ++i) { r[i] = (f16)a[i]; r[4 + i] = (f16)b[i]; }
  return r;
}

__global__ __launch_bounds__(256, 1)
void lstm2_kernel(const float* __restrict__ x,
                  const float* __restrict__ Wih0, const float* __restrict__ Whh0,
                  const float* __restrict__ bih0, const float* __restrict__ bhh0,
                  const float* __restrict__ Wih1, const float* __restrict__ Whh1,
                  const float* __restrict__ bih1, const float* __restrict__ bhh1,
                  const float* __restrict__ Wlin, const float* __restrict__ blin,
                  float* __restrict__ out)
{
  extern __shared__ f16 lds[];
  f16* xstage = lds;
  f16* aug0 = lds + A0OFF;
  f16* aug1 = lds + A1OFF;

  const int tid = threadIdx.x;
  const int w = tid >> 6;          // wave 0..3: units [16w, 16w+16)
  const int lane = tid & 63;
  const int m = lane & 15;         // A-fragment row / B col (batch)
  const int q = lane >> 4;         // k-quarter / C row group

  // ---- load weights as A fragments (registers, once) + biases into C-init ----
  f16x8 a0f[4][3], a1f[4][4];
  f32x4 b0v[4], b1v[4];
  #pragma unroll
  for (int g = 0; g < 4; ++g) {
    const int R = g * 64 + 16 * w + m;
    a1f[g][0] = cvt8(&Whh1[R * 64 + 8 * q]);
    a1f[g][1] = cvt8(&Whh1[R * 64 + 32 + 8 * q]);
    a1f[g][2] = cvt8(&Wih1[R * 64 + 8 * q]);
    a1f[g][3] = cvt8(&Wih1[R * 64 + 32 + 8 * q]);
    a0f[g][0] = cvt8(&Whh0[R * 64 + 8 * q]);
    a0f[g][1] = cvt8(&Whh0[R * 64 + 32 + 8 * q]);
    f16x8 t;
    #pragma unroll
    for (int i = 0; i < 8; ++i) t[i] = (f16)0.0f;
    if (q == 0) {
      #pragma unroll
      for (int i = 0; i < 6; ++i) t[i] = (f16)Wih0[R * 6 + i];
    }
    a0f[g][2] = t;
    const int U = g * 64 + 16 * w + 4 * q;   // bias rows for C fragment (row = 4q + r)
    #pragma unroll
    for (int r = 0; r < 4; ++r) {
      b0v[g][r] = bih0[U + r] + bhh0[U + r];
      b1v[g][r] = bih1[U + r] + bhh1[U + r];
    }
  }

  // ---- stage x -> LDS f16 (coalesced float4) ----
  {
    const float* xblk = x + (size_t)blockIdx.x * XS_ELE;
    for (int idx = tid; idx < XS_ELE / 4; idx += 256) {
      f32x4 v = *(const f32x4*)&xblk[idx * 4];
      f16x4 h;
      #pragma unroll
      for (int i = 0; i < 4; ++i) h[i] = (f16)v[i];
      *(f16x4*)&xstage[idx * 4] = h;
    }
  }
  // ---- zero both aug buffers ----
  for (int idx = tid; idx < 2 * NB * AUGS; idx += 256) aug0[idx] = (f16)0.0f;
  __syncthreads();
  // x_0 -> aug0
  if (tid < 128) {
    const int n = tid >> 3, i = tid & 7;
    if (i < 6) aug0[n * AUGS + 128 + i] = xstage[n * 3072 + i];
  }
  __syncthreads();

  f32x4 c1v, c2v;
  #pragma unroll
  for (int r = 0; r < 4; ++r) { c1v[r] = 0.0f; c2v[r] = 0.0f; }

  const int colb = m * AUGS;
  const int hwofs = 16 * w + 4 * q;

  auto step = [&](f16* cur, f16* nxt, int t) {
    // ---- layer 0: gates0 = b0 + [Whh0|Wih0] . cur[h1|x] ----
    f16x8 B0[3];
    #pragma unroll
    for (int kt = 0; kt < 3; ++kt)
      B0[kt] = *(const f16x8*)&cur[colb + 64 + 32 * kt + 8 * q];
    f32x4 acc[4];
    #pragma unroll
    for (int g = 0; g < 4; ++g) acc[g] = b0v[g];
    #pragma unroll
    for (int kt = 0; kt < 3; ++kt)
      #pragma unroll
      for (int g = 0; g < 4; ++g)
        acc[g] = __builtin_amdgcn_mfma_f32_16x16x32_f16(a0f[g][kt], B0[kt], acc[g], 0, 0, 0);
    f16x4 h1o;
    #pragma unroll
    for (int r = 0; r < 4; ++r) {
      float iv = sigm(acc[0][r]);
      float fv = sigm(acc[1][r]);
      float gv = tanhq(acc[2][r]);
      float ov = sigm(acc[3][r]);
      float cn = fv * c1v[r] + iv * gv;
      c1v[r] = cn;
      h1o[r] = (f16)(ov * tanhq(cn));
    }
    *(f16x4*)&nxt[colb + 64 + hwofs] = h1o;
    __syncthreads();
    // ---- layer 1: gates1 = b1 + [Whh1|Wih1] . [cur.h2 | nxt.h1] ----
    f16x8 B1[4];
    B1[0] = *(const f16x8*)&cur[colb + 0 + 8 * q];
    B1[1] = *(const f16x8*)&cur[colb + 32 + 8 * q];
    B1[2] = *(const f16x8*)&nxt[colb + 64 + 8 * q];
    B1[3] = *(const f16x8*)&nxt[colb + 96 + 8 * q];
    #pragma unroll
    for (int g = 0; g < 4; ++g) acc[g] = b1v[g];
    #pragma unroll
    for (int kt = 0; kt < 4; ++kt)
      #pragma unroll
      for (int g = 0; g < 4; ++g)
        acc[g] = __builtin_amdgcn_mfma_f32_16x16x32_f16(a1f[g][kt], B1[kt], acc[g], 0, 0, 0);
    f16x4 h2o;
    #pragma unroll
    for (int r = 0; r < 4; ++r) {
      float iv = sigm(acc[0][r]);
      float fv = sigm(acc[1][r]);
      float gv = tanhq(acc[2][r]);
      float ov = sigm(acc[3][r]);
      float cn = fv * c2v[r] + iv * gv;
      c2v[r] = cn;
      h2o[r] = (f16)(ov * tanhq(cn));
    }
    *(f16x4*)&nxt[colb + hwofs] = h2o;
    // stage x_{t+1} into nxt
    if (t < TT - 1 && tid < 128) {
      const int n = tid >> 3, i = tid & 7;
      if (i < 6) nxt[n * AUGS + 128 + i] = xstage[n * 3072 + (t + 1) * 6 + i];
    }
    __syncthreads();
  };

  #pragma unroll 1
  for (int t = 0; t < TT; t += 2) {
    step(aug0, aug1, t);
    step(aug1, aug0, t + 1);
  }
  // final h2 (t=511) was written into aug0

  // ---- final linear ----
  if (tid < 96) {
    const int bl = tid / 6, o = tid - bl * 6;
    float s = blin[o];
    const float* wl = &Wlin[o * 64];
    #pragma unroll 8
    for (int u = 0; u < 64; ++u) s += wl[u] * (float)aug0[bl * AUGS + u];
    out[(blockIdx.x * NB + bl) * 6 + o] = s;
  }
}

extern "C" void kernel_launch(void* const* d_in, const int* in_sizes, int n_in,
                              void* d_out, int out_size, void* d_ws, size_t ws_size,
                              hipStream_t stream) {
  const float* xp    = (const float*)d_in[0];
  const float* Wih0  = (const float*)d_in[1];
  const float* Whh0  = (const float*)d_in[2];
  const float* bih0  = (const float*)d_in[3];
  const float* bhh0  = (const float*)d_in[4];
  const float* Wih1  = (const float*)d_in[5];
  const float* Whh1  = (const float*)d_in[6];
  const float* bih1  = (const float*)d_in[7];
  const float* bhh1  = (const float*)d_in[8];
  const float* Wlin  = (const float*)d_in[9];
  const float* blin  = (const float*)d_in[10];
  float* outp = (float*)d_out;

  hipFuncSetAttribute(reinterpret_cast<const void*>(lstm2_kernel),
                      hipFuncAttributeMaxDynamicSharedMemorySize, LDS_BYTES);
  lstm2_kernel<<<128, 256, LDS_BYTES, stream>>>(xp, Wih0, Whh0, bih0, bhh0,
                                                Wih1, Whh1, bih1, bhh1,
                                                Wlin, blin, outp);
}

// Round 9
// 467.072 us; speedup vs baseline: 5.9072x; 1.7919x over previous
//
#include <hip/hip_runtime.h>

typedef _Float16 f16;
typedef _Float16 f16x4 __attribute__((ext_vector_type(4)));
typedef _Float16 f16x8 __attribute__((ext_vector_type(8)));
typedef float f32x4 __attribute__((ext_vector_type(4)));

__device__ __forceinline__ float fastrcp(float x) { return __builtin_amdgcn_rcpf(x); }
__device__ __forceinline__ float sigm(float z) { return fastrcp(1.0f + __expf(-z)); }
__device__ __forceinline__ float tanhq(float z) {
  return 1.0f - 2.0f * fastrcp(1.0f + __expf(2.0f * z));
}

#define TT 512
#define NB 16
/* xstage: f16 [NB][3080]  (3072 data + 8 pad; dw stride 1540 -> m*4 mod 32, 2-way = free) */
#define XBS 3080
#define XS_ELE (NB * XBS)            /* 49280 */
/* aug: [h2(64)|h1(64)|slack] stride 184 f16 = 368B = 92dw (16B-aligned; m*28 mod 32 -> 2-way = free) */
#define AUGS 184
#define A0OFF XS_ELE
#define A1OFF (A0OFF + NB * AUGS)
#define LDS_F16 (A1OFF + NB * AUGS)  /* 55168 */
#define LDS_BYTES (LDS_F16 * 2)      /* 110336 B */

__device__ __forceinline__ f16x8 cvt8(const float* p) {
  f32x4 a = *(const f32x4*)p;
  f32x4 b = *(const f32x4*)(p + 4);
  f16x8 r;
  #pragma unroll
  for (int i = 0; i < 4; ++i) { r[i] = (f16)a[i]; r[4 + i] = (f16)b[i]; }
  return r;
}

__global__ __launch_bounds__(256, 1)
void lstm2_kernel(const float* __restrict__ x,
                  const float* __restrict__ Wih0, const float* __restrict__ Whh0,
                  const float* __restrict__ bih0, const float* __restrict__ bhh0,
                  const float* __restrict__ Wih1, const float* __restrict__ Whh1,
                  const float* __restrict__ bih1, const float* __restrict__ bhh1,
                  const float* __restrict__ Wlin, const float* __restrict__ blin,
                  float* __restrict__ out)
{
  extern __shared__ f16 lds[];
  f16* xstage = lds;
  f16* aug0 = lds + A0OFF;
  f16* aug1 = lds + A1OFF;
  const unsigned int* xw = (const unsigned int*)xstage;

  const int tid = threadIdx.x;
  const int w = tid >> 6;          // wave: units [16w, 16w+16)
  const int lane = tid & 63;
  const int m = lane & 15;         // batch column
  const int q = lane >> 4;         // k-quarter / C row group

  // ---- stationary weights: A fragments in registers ----
  f16x8 a0f[4][3], a1f[4][4];
  f32x4 b0v[4], b1v[4];
  #pragma unroll
  for (int g = 0; g < 4; ++g) {
    const int R = g * 64 + 16 * w + m;
    a1f[g][0] = cvt8(&Whh1[R * 64 + 8 * q]);
    a1f[g][1] = cvt8(&Whh1[R * 64 + 32 + 8 * q]);
    a1f[g][2] = cvt8(&Wih1[R * 64 + 8 * q]);
    a1f[g][3] = cvt8(&Wih1[R * 64 + 32 + 8 * q]);
    a0f[g][0] = cvt8(&Whh0[R * 64 + 8 * q]);
    a0f[g][1] = cvt8(&Whh0[R * 64 + 32 + 8 * q]);
    f16x8 t;
    #pragma unroll
    for (int i = 0; i < 8; ++i) t[i] = (f16)0.0f;
    if (q == 0) {
      #pragma unroll
      for (int i = 0; i < 6; ++i) t[i] = (f16)Wih0[R * 6 + i];
    }
    a0f[g][2] = t;
    const int U = g * 64 + 16 * w + 4 * q;
    #pragma unroll
    for (int r = 0; r < 4; ++r) {
      b0v[g][r] = bih0[U + r] + bhh0[U + r];
      b1v[g][r] = bih1[U + r] + bhh1[U + r];
    }
  }

  // ---- stage x -> LDS f16, padded stride (coalesced f32x4) ----
  {
    const float* xblk = x + (size_t)blockIdx.x * (NB * TT * 6);
    #pragma unroll 1
    for (int n = 0; n < NB; ++n) {
      const float* src = xblk + n * (TT * 6);
      f16* dst = xstage + n * XBS;
      for (int idx = tid; idx < TT * 6 / 4; idx += 256) {
        f32x4 v = *(const f32x4*)&src[idx * 4];
        f16x4 h;
        #pragma unroll
        for (int i = 0; i < 4; ++i) h[i] = (f16)v[i];
        *(f16x4*)&dst[idx * 4] = h;
      }
    }
  }
  // ---- zero aug0 (h2(-1)=0, h1 cleared before prologue fills it) ----
  for (int idx = tid; idx < NB * AUGS; idx += 256) aug0[idx] = (f16)0.0f;
  __syncthreads();

  f32x4 c1v, c2v;
  #pragma unroll
  for (int r = 0; r < 4; ++r) { c1v[r] = 0.0f; c2v[r] = 0.0f; }

  const int colb = m * AUGS;
  const int xdw = m * (XBS / 2);          // dword base of this batch's x
  const int hwofs = 16 * w + 4 * q;

  // ---- prologue: L0(0) = b0 + Wih0 . x(0)  (h1_prev = 0 -> skip those tiles) ----
  {
    union { unsigned int u[4]; f16x8 h; } bx;
    bx.u[0] = xw[xdw + 0]; bx.u[1] = xw[xdw + 1]; bx.u[2] = xw[xdw + 2]; bx.u[3] = 0u;
    f32x4 acc[4];
    #pragma unroll
    for (int g = 0; g < 4; ++g)
      acc[g] = __builtin_amdgcn_mfma_f32_16x16x32_f16(a0f[g][2], bx.h, b0v[g], 0, 0, 0);
    f16x4 h1o;
    #pragma unroll
    for (int r = 0; r < 4; ++r) {
      float iv = sigm(acc[0][r]);
      float fv = sigm(acc[1][r]);
      float gv = tanhq(acc[2][r]);
      float ov = sigm(acc[3][r]);
      float cn = fv * c1v[r] + iv * gv;
      c1v[r] = cn;
      h1o[r] = (f16)(ov * tanhq(cn));
    }
    *(f16x4*)&aug0[colb + 64 + hwofs] = h1o;
  }
  __syncthreads();

  // ---- main loop: body(t) = L1(t) + L0(t+1); ONE barrier/step ----
  f16* cur = aug0;
  f16* nxt = aug1;
  #pragma unroll 1
  for (int t = 0; t < TT - 1; ++t) {
    // B fragments (all from cur / xstage)
    f16x8 Bh2a = *(const f16x8*)&cur[colb + 0 + 8 * q];
    f16x8 Bh2b = *(const f16x8*)&cur[colb + 32 + 8 * q];
    f16x8 Bh1a = *(const f16x8*)&cur[colb + 64 + 8 * q];
    f16x8 Bh1b = *(const f16x8*)&cur[colb + 96 + 8 * q];
    union { unsigned int u[4]; f16x8 h; } bx;
    const int xo = xdw + 3 * (t + 1);
    bx.u[0] = xw[xo]; bx.u[1] = xw[xo + 1]; bx.u[2] = xw[xo + 2]; bx.u[3] = 0u;

    // L1(t): gates1 = b1 + Whh1.h2(t-1) + Wih1.h1(t)
    f32x4 acc1[4];
    #pragma unroll
    for (int g = 0; g < 4; ++g) {
      f32x4 a = __builtin_amdgcn_mfma_f32_16x16x32_f16(a1f[g][0], Bh2a, b1v[g], 0, 0, 0);
      a = __builtin_amdgcn_mfma_f32_16x16x32_f16(a1f[g][1], Bh2b, a, 0, 0, 0);
      a = __builtin_amdgcn_mfma_f32_16x16x32_f16(a1f[g][2], Bh1a, a, 0, 0, 0);
      acc1[g] = __builtin_amdgcn_mfma_f32_16x16x32_f16(a1f[g][3], Bh1b, a, 0, 0, 0);
    }
    // L0(t+1): gates0 = b0 + Whh0.h1(t) + Wih0.x(t+1)
    f32x4 acc0[4];
    #pragma unroll
    for (int g = 0; g < 4; ++g) {
      f32x4 a = __builtin_amdgcn_mfma_f32_16x16x32_f16(a0f[g][0], Bh1a, b0v[g], 0, 0, 0);
      a = __builtin_amdgcn_mfma_f32_16x16x32_f16(a0f[g][1], Bh1b, a, 0, 0, 0);
      acc0[g] = __builtin_amdgcn_mfma_f32_16x16x32_f16(a0f[g][2], bx.h, a, 0, 0, 0);
    }

    // pointwise L1(t) -> h2(t)
    f16x4 h2o, h1o;
    #pragma unroll
    for (int r = 0; r < 4; ++r) {
      float iv = sigm(acc1[0][r]);
      float fv = sigm(acc1[1][r]);
      float gv = tanhq(acc1[2][r]);
      float ov = sigm(acc1[3][r]);
      float cn = fv * c2v[r] + iv * gv;
      c2v[r] = cn;
      h2o[r] = (f16)(ov * tanhq(cn));
    }
    // pointwise L0(t+1) -> h1(t+1)
    #pragma unroll
    for (int r = 0; r < 4; ++r) {
      float iv = sigm(acc0[0][r]);
      float fv = sigm(acc0[1][r]);
      float gv = tanhq(acc0[2][r]);
      float ov = sigm(acc0[3][r]);
      float cn = fv * c1v[r] + iv * gv;
      c1v[r] = cn;
      h1o[r] = (f16)(ov * tanhq(cn));
    }
    *(f16x4*)&nxt[colb + 0 + hwofs] = h2o;     // h2(t)
    *(f16x4*)&nxt[colb + 64 + hwofs] = h1o;    // h1(t+1)
    __syncthreads();
    f16* tmp = cur; cur = nxt; nxt = tmp;
  }

  // ---- epilogue: L1(511) from cur{h2(510), h1(511)} ----
  {
    f16x8 Bh2a = *(const f16x8*)&cur[colb + 0 + 8 * q];
    f16x8 Bh2b = *(const f16x8*)&cur[colb + 32 + 8 * q];
    f16x8 Bh1a = *(const f16x8*)&cur[colb + 64 + 8 * q];
    f16x8 Bh1b = *(const f16x8*)&cur[colb + 96 + 8 * q];
    f32x4 acc1[4];
    #pragma unroll
    for (int g = 0; g < 4; ++g) {
      f32x4 a = __builtin_amdgcn_mfma_f32_16x16x32_f16(a1f[g][0], Bh2a, b1v[g], 0, 0, 0);
      a = __builtin_amdgcn_mfma_f32_16x16x32_f16(a1f[g][1], Bh2b, a, 0, 0, 0);
      a = __builtin_amdgcn_mfma_f32_16x16x32_f16(a1f[g][2], Bh1a, a, 0, 0, 0);
      acc1[g] = __builtin_amdgcn_mfma_f32_16x16x32_f16(a1f[g][3], Bh1b, a, 0, 0, 0);
    }
    f16x4 h2o;
    #pragma unroll
    for (int r = 0; r < 4; ++r) {
      float iv = sigm(acc1[0][r]);
      float fv = sigm(acc1[1][r]);
      float gv = tanhq(acc1[2][r]);
      float ov = sigm(acc1[3][r]);
      float cn = fv * c2v[r] + iv * gv;
      h2o[r] = (f16)(ov * tanhq(cn));
    }
    *(f16x4*)&nxt[colb + hwofs] = h2o;   // final h2 into nxt's h2 slot (no race: nxt not read here)
  }
  __syncthreads();

  // ---- final linear ----
  if (tid < 96) {
    const int bl = tid / 6, o = tid - bl * 6;
    float s = blin[o];
    const float* wl = &Wlin[o * 64];
    #pragma unroll 8
    for (int u = 0; u < 64; ++u) s += wl[u] * (float)nxt[bl * AUGS + u];
    out[(blockIdx.x * NB + bl) * 6 + o] = s;
  }
}

extern "C" void kernel_launch(void* const* d_in, const int* in_sizes, int n_in,
                              void* d_out, int out_size, void* d_ws, size_t ws_size,
                              hipStream_t stream) {
  const float* xp    = (const float*)d_in[0];
  const float* Wih0  = (const float*)d_in[1];
  const float* Whh0  = (const float*)d_in[2];
  const float* bih0  = (const float*)d_in[3];
  const float* bhh0  = (const float*)d_in[4];
  const float* Wih1  = (const float*)d_in[5];
  const float* Whh1  = (const float*)d_in[6];
  const float* bih1  = (const float*)d_in[7];
  const float* bhh1  = (const float*)d_in[8];
  const float* Wlin  = (const float*)d_in[9];
  const float* blin  = (const float*)d_in[10];
  float* outp = (float*)d_out;

  hipFuncSetAttribute(reinterpret_cast<const void*>(lstm2_kernel),
                      hipFuncAttributeMaxDynamicSharedMemorySize, LDS_BYTES);
  lstm2_kernel<<<128, 256, LDS_BYTES, stream>>>(xp, Wih0, Whh0, bih0, bhh0,
                                                Wih1, Whh1, bih1, bhh1,
                                                Wlin, blin, outp);
}

// Round 10
// 404.776 us; speedup vs baseline: 6.8164x; 1.1539x over previous
//
#include <hip/hip_runtime.h>

typedef _Float16 f16;
typedef _Float16 f16x4 __attribute__((ext_vector_type(4)));
typedef _Float16 f16x8 __attribute__((ext_vector_type(8)));
typedef float f32x4 __attribute__((ext_vector_type(4)));

__device__ __forceinline__ float fastrcp(float x) { return __builtin_amdgcn_rcpf(x); }
__device__ __forceinline__ float sigm(float z) { return fastrcp(1.0f + __expf(-z)); }
__device__ __forceinline__ float tanhq(float z) {
  return 1.0f - 2.0f * fastrcp(1.0f + __expf(2.0f * z));
}

#define TT 512
#define NB 16
/* xstage: f16 [NB][3080] ; dw stride 1540 (== 4 mod 32) */
#define XBS 3080
#define XS_ELE (NB * XBS)            /* 49280 */
/* aug: [h2(64)|h1(64)|pad(8)] stride 136 f16 = 68 dw (== 4 mod 32 -> b128 reads at the 8-phase floor) */
#define AUGS 136
#define A0OFF XS_ELE
#define A1OFF (A0OFF + NB * AUGS)
#define LDS_F16 (A1OFF + NB * AUGS)  /* 53632 */
#define LDS_BYTES (LDS_F16 * 2)      /* 107264 B */

__device__ __forceinline__ f16x8 cvt8(const float* p) {
  f32x4 a = *(const f32x4*)p;
  f32x4 b = *(const f32x4*)(p + 4);
  f16x8 r;
  #pragma unroll
  for (int i = 0; i < 4; ++i) { r[i] = (f16)a[i]; r[4 + i] = (f16)b[i]; }
  return r;
}

__global__ __launch_bounds__(512, 2)
void lstm2_kernel(const float* __restrict__ x,
                  const float* __restrict__ Wih0, const float* __restrict__ Whh0,
                  const float* __restrict__ bih0, const float* __restrict__ bhh0,
                  const float* __restrict__ Wih1, const float* __restrict__ Whh1,
                  const float* __restrict__ bih1, const float* __restrict__ bhh1,
                  const float* __restrict__ Wlin, const float* __restrict__ blin,
                  float* __restrict__ out)
{
  extern __shared__ f16 lds[];
  f16* xstage = lds;
  f16* aug0 = lds + A0OFF;
  f16* aug1 = lds + A1OFF;
  const unsigned int* xw = (const unsigned int*)xstage;

  const int tid = threadIdx.x;
  const int wv = tid >> 6;
  const int team = wv >> 2;        // 0: layer-0 pipeline stage, 1: layer-1 stage
  const int uw = wv & 3;           // unit group [16*uw, 16*uw+16)
  const int lane = tid & 63;
  const int m = lane & 15;         // batch column
  const int q = lane >> 4;         // k-quarter / C row group

  // ---- per-team stationary weights (A fragments) + biases ----
  f16x8 af[4][4];
  f32x4 bv[4];
  if (team == 1) {
    #pragma unroll
    for (int g = 0; g < 4; ++g) {
      const int R = g * 64 + 16 * uw + m;
      af[g][0] = cvt8(&Whh1[R * 64 + 8 * q]);
      af[g][1] = cvt8(&Whh1[R * 64 + 32 + 8 * q]);
      af[g][2] = cvt8(&Wih1[R * 64 + 8 * q]);
      af[g][3] = cvt8(&Wih1[R * 64 + 32 + 8 * q]);
      const int U = g * 64 + 16 * uw + 4 * q;
      #pragma unroll
      for (int r = 0; r < 4; ++r) bv[g][r] = bih1[U + r] + bhh1[U + r];
    }
  } else {
    #pragma unroll
    for (int g = 0; g < 4; ++g) {
      const int R = g * 64 + 16 * uw + m;
      af[g][0] = cvt8(&Whh0[R * 64 + 8 * q]);
      af[g][1] = cvt8(&Whh0[R * 64 + 32 + 8 * q]);
      f16x8 t;
      #pragma unroll
      for (int i = 0; i < 8; ++i) t[i] = (f16)0.0f;
      if (q == 0) {
        #pragma unroll
        for (int i = 0; i < 6; ++i) t[i] = (f16)Wih0[R * 6 + i];
      }
      af[g][2] = t;
      af[g][3] = t;  // unused by team 0
      const int U = g * 64 + 16 * uw + 4 * q;
      #pragma unroll
      for (int r = 0; r < 4; ++r) bv[g][r] = bih0[U + r] + bhh0[U + r];
    }
  }

  // ---- stage x -> LDS f16 (coalesced f32x4) ----
  {
    const float* xblk = x + (size_t)blockIdx.x * (NB * TT * 6);
    #pragma unroll 1
    for (int n = 0; n < NB; ++n) {
      const float* src = xblk + n * (TT * 6);
      f16* dst = xstage + n * XBS;
      for (int idx = tid; idx < TT * 6 / 4; idx += 512) {
        f32x4 v = *(const f32x4*)&src[idx * 4];
        f16x4 h;
        #pragma unroll
        for (int i = 0; i < 4; ++i) h[i] = (f16)v[i];
        *(f16x4*)&dst[idx * 4] = h;
      }
    }
  }
  for (int idx = tid; idx < NB * AUGS; idx += 512) aug0[idx] = (f16)0.0f;
  __syncthreads();

  f32x4 cstate;
  #pragma unroll
  for (int r = 0; r < 4; ++r) cstate[r] = 0.0f;

  const int colb = m * AUGS;
  const int xdw = m * (XBS / 2);
  const int hwofs = 16 * uw + 4 * q;

  auto pointwise = [&](const f32x4* acc, f32x4& cs) -> f16x4 {
    f16x4 ho;
    #pragma unroll
    for (int r = 0; r < 4; ++r) {
      float iv = sigm(acc[0][r]);
      float fv = sigm(acc[1][r]);
      float gv = tanhq(acc[2][r]);
      float ov = sigm(acc[3][r]);
      float cn = fv * cs[r] + iv * gv;
      cs[r] = cn;
      ho[r] = (f16)(ov * tanhq(cn));
    }
    return ho;
  };

  // ---- prologue: team0 computes h1(0) = L0(x(0), h1(-1)=0) ----
  if (team == 0) {
    union { unsigned int u[4]; f16x8 h; } bx;
    bx.u[0] = xw[xdw + 0]; bx.u[1] = xw[xdw + 1]; bx.u[2] = xw[xdw + 2]; bx.u[3] = 0u;
    f32x4 acc[4];
    #pragma unroll
    for (int g = 0; g < 4; ++g)
      acc[g] = __builtin_amdgcn_mfma_f32_16x16x32_f16(af[g][2], bx.h, bv[g], 0, 0, 0);
    f16x4 h1o = pointwise(acc, cstate);
    *(f16x4*)&aug0[colb + 64 + hwofs] = h1o;
  }
  __syncthreads();

  // ---- main loop: team1 does L1(t), team0 does L0(t+1), concurrently; 1 barrier/step ----
  f16* cur = aug0;
  f16* nxt = aug1;
  #pragma unroll 1
  for (int t = 0; t < TT - 1; ++t) {
    f16x8 Bh1a = *(const f16x8*)&cur[colb + 64 + 8 * q];
    f16x8 Bh1b = *(const f16x8*)&cur[colb + 96 + 8 * q];
    if (team == 1) {
      f16x8 Bh2a = *(const f16x8*)&cur[colb + 0 + 8 * q];
      f16x8 Bh2b = *(const f16x8*)&cur[colb + 32 + 8 * q];
      f32x4 acc[4];
      #pragma unroll
      for (int g = 0; g < 4; ++g) {
        f32x4 a = __builtin_amdgcn_mfma_f32_16x16x32_f16(af[g][0], Bh2a, bv[g], 0, 0, 0);
        a = __builtin_amdgcn_mfma_f32_16x16x32_f16(af[g][1], Bh2b, a, 0, 0, 0);
        a = __builtin_amdgcn_mfma_f32_16x16x32_f16(af[g][2], Bh1a, a, 0, 0, 0);
        acc[g] = __builtin_amdgcn_mfma_f32_16x16x32_f16(af[g][3], Bh1b, a, 0, 0, 0);
      }
      f16x4 h2o = pointwise(acc, cstate);
      *(f16x4*)&nxt[colb + hwofs] = h2o;                 // h2(t)
    } else {
      union { unsigned int u[4]; f16x8 h; } bx;
      const int xo = xdw + 3 * (t + 1);
      bx.u[0] = xw[xo]; bx.u[1] = xw[xo + 1]; bx.u[2] = xw[xo + 2]; bx.u[3] = 0u;
      f32x4 acc[4];
      #pragma unroll
      for (int g = 0; g < 4; ++g) {
        f32x4 a = __builtin_amdgcn_mfma_f32_16x16x32_f16(af[g][0], Bh1a, bv[g], 0, 0, 0);
        a = __builtin_amdgcn_mfma_f32_16x16x32_f16(af[g][1], Bh1b, a, 0, 0, 0);
        acc[g] = __builtin_amdgcn_mfma_f32_16x16x32_f16(af[g][2], bx.h, a, 0, 0, 0);
      }
      f16x4 h1o = pointwise(acc, cstate);
      *(f16x4*)&nxt[colb + 64 + hwofs] = h1o;            // h1(t+1)
    }
    __syncthreads();
    f16* tmp = cur; cur = nxt; nxt = tmp;
  }

  // ---- epilogue: team1 computes h2(511) into nxt ----
  if (team == 1) {
    f16x8 Bh2a = *(const f16x8*)&cur[colb + 0 + 8 * q];
    f16x8 Bh2b = *(const f16x8*)&cur[colb + 32 + 8 * q];
    f16x8 Bh1a = *(const f16x8*)&cur[colb + 64 + 8 * q];
    f16x8 Bh1b = *(const f16x8*)&cur[colb + 96 + 8 * q];
    f32x4 acc[4];
    #pragma unroll
    for (int g = 0; g < 4; ++g) {
      f32x4 a = __builtin_amdgcn_mfma_f32_16x16x32_f16(af[g][0], Bh2a, bv[g], 0, 0, 0);
      a = __builtin_amdgcn_mfma_f32_16x16x32_f16(af[g][1], Bh2b, a, 0, 0, 0);
      a = __builtin_amdgcn_mfma_f32_16x16x32_f16(af[g][2], Bh1a, a, 0, 0, 0);
      acc[g] = __builtin_amdgcn_mfma_f32_16x16x32_f16(af[g][3], Bh1b, a, 0, 0, 0);
    }
    f16x4 h2o = pointwise(acc, cstate);
    *(f16x4*)&nxt[colb + hwofs] = h2o;
  }
  __syncthreads();

  // ---- final linear ----
  if (tid < 96) {
    const int bl = tid / 6, o = tid - bl * 6;
    float s = blin[o];
    const float* wl = &Wlin[o * 64];
    #pragma unroll 8
    for (int u = 0; u < 64; ++u) s += wl[u] * (float)nxt[bl * AUGS + u];
    out[(blockIdx.x * NB + bl) * 6 + o] = s;
  }
}

extern "C" void kernel_launch(void* const* d_in, const int* in_sizes, int n_in,
                              void* d_out, int out_size, void* d_ws, size_t ws_size,
                              hipStream_t stream) {
  const float* xp    = (const float*)d_in[0];
  const float* Wih0  = (const float*)d_in[1];
  const float* Whh0  = (const float*)d_in[2];
  const float* bih0  = (const float*)d_in[3];
  const float* bhh0  = (const float*)d_in[4];
  const float* Wih1  = (const float*)d_in[5];
  const float* Whh1  = (const float*)d_in[6];
  const float* bih1  = (const float*)d_in[7];
  const float* bhh1  = (const float*)d_in[8];
  const float* Wlin  = (const float*)d_in[9];
  const float* blin  = (const float*)d_in[10];
  float* outp = (float*)d_out;

  hipFuncSetAttribute(reinterpret_cast<const void*>(lstm2_kernel),
                      hipFuncAttributeMaxDynamicSharedMemorySize, LDS_BYTES);
  lstm2_kernel<<<128, 512, LDS_BYTES, stream>>>(xp, Wih0, Whh0, bih0, bhh0,
                                                Wih1, Whh1, bih1, bhh1,
                                                Wlin, blin, outp);
}